// Round 1
// baseline (246.230 us; speedup 1.0000x reference)
//
#include <hip/hip_runtime.h>

// FCOS decode, level stride=8.
// Inputs:  t_ltrb [32,128,128,4] f32, center_logits [32,128,128,1] f32,
//          cls_logits [32,128,128,80] f32, img_h (unused), img_w (unused)
// Outputs (concat flat, all f32): xywh [nPix*4] | cls_idx [nPix] | conf [nPix]
//
// 4 lanes per *pair* of pixels: lane l issues 10 independent float4 loads
// (5 per pixel); each 4-lane group covers full 64B segments -> fully
// coalesced wave loads, 10 loads in flight per lane.
//
// Changes vs previous version (239.1 us):
//  - cls/ltrb/center loads are now CACHED (no `nt`): inputs (178 MB) fit in
//    the 256 MiB Infinity Cache and were just written by the poison fill;
//    nontemporal loads forced pure-HBM streaming. Stores stay nontemporal
//    (outputs are single-use, keep them out of L2/LLC).
//  - epilogue split across lanes 0 and 1 of each group (lane l owns pixel
//    p0+l; the XOR-reduce leaves both results in all 4 lanes) -> ltrb loads
//    and all output stores are 32-lane contiguous instead of 16-lane
//    stride-2 pairs.
//  - ltrb/center loads hoisted above the shuffle reduce so their latency
//    hides under the cross-lane chain.

#define NB   32
#define NH   128
#define NW   128
#define NC   80
#define HWPX (NH * NW)          // 16384
#define NPIX (NB * HWPX)        // 524288

typedef float f4 __attribute__((ext_vector_type(4)));

__device__ __forceinline__ float fast_sigmoid(float x) {
    return 1.0f / (1.0f + __expf(-x));
}

__global__ __launch_bounds__(256) void fcos_decode_kernel(
    const float* __restrict__ t_ltrb,
    const float* __restrict__ center_logits,
    const float* __restrict__ cls_logits,
    float* __restrict__ out)
{
    int tid = blockIdx.x * blockDim.x + threadIdx.x;
    int grp = tid >> 2;          // each 4-lane group handles 2 pixels
    int l   = tid & 3;
    int p0  = grp * 2;
    if (p0 >= NPIX) return;

    const f4* cp0 = reinterpret_cast<const f4*>(cls_logits) + (size_t)p0 * (NC / 4);
    const f4* cp1 = cp0 + (NC / 4);

    // Issue all 10 independent loads up front (cached: LLC can serve them).
    f4 va[5], vb[5];
    #pragma unroll
    for (int k = 0; k < 5; ++k) va[k] = cp0[k * 4 + l];
    #pragma unroll
    for (int k = 0; k < 5; ++k) vb[k] = cp1[k * 4 + l];

    // Epilogue operands: issue early so latency hides under the reduce.
    // Lane l<2 will own pixel p0+l.
    f4 t4 = {0.f, 0.f, 0.f, 0.f};
    float cl_ = 0.f;
    if (l < 2) {
        t4  = reinterpret_cast<const f4*>(t_ltrb)[p0 + l];
        cl_ = center_logits[p0 + l];
    }

    // Per-lane argmax (sigmoid monotonic -> argmax on raw logits; strict '>'
    // + ascending index = first occurrence, matching np.argmax).
    float b0 = -INFINITY, b1 = -INFINITY;
    int i0 = 0, i1 = 0;
    #pragma unroll
    for (int k = 0; k < 5; ++k) {
        int c = k * 16 + l * 4;
        f4 v = va[k];
        if (v.x > b0) { b0 = v.x; i0 = c + 0; }
        if (v.y > b0) { b0 = v.y; i0 = c + 1; }
        if (v.z > b0) { b0 = v.z; i0 = c + 2; }
        if (v.w > b0) { b0 = v.w; i0 = c + 3; }
        f4 w = vb[k];
        if (w.x > b1) { b1 = w.x; i1 = c + 0; }
        if (w.y > b1) { b1 = w.y; i1 = c + 1; }
        if (w.z > b1) { b1 = w.z; i1 = c + 2; }
        if (w.w > b1) { b1 = w.w; i1 = c + 3; }
    }
    // Cross-lane reduce over the 4-lane group; smaller index wins ties.
    // After both steps every lane in the group holds (b0,i0) and (b1,i1).
    #pragma unroll
    for (int m = 2; m >= 1; m >>= 1) {
        float ov0 = __shfl_xor(b0, m, 4);
        int   oi0 = __shfl_xor(i0, m, 4);
        if (ov0 > b0 || (ov0 == b0 && oi0 < i0)) { b0 = ov0; i0 = oi0; }
        float ov1 = __shfl_xor(b1, m, 4);
        int   oi1 = __shfl_xor(i1, m, 4);
        if (ov1 > b1 || (ov1 == b1 && oi1 < i1)) { b1 = ov1; i1 = oi1; }
    }

    if (l < 2) {
        int pix = p0 + l;                 // lane 0 -> p0, lane 1 -> p0+1
        float bv = l ? b1 : b0;
        int   bi = l ? i1 : i0;

        int pimg = pix & (HWPX - 1);
        int gy = pimg >> 7;
        int gx = pimg & (NW - 1);

        float pl = __expf(t4.x) * 8.0f;
        float pt = __expf(t4.y) * 8.0f;
        float pr = __expf(t4.z) * 8.0f;
        float pb = __expf(t4.w) * 8.0f;

        f4 r;
        r.x = ((float)gx * 8.0f + 4.0f) + (pr - pl) * 0.5f;  // cx
        r.y = ((float)gy * 8.0f + 4.0f) + (pb - pt) * 0.5f;  // cy
        r.z = pl + pr;                                        // w
        r.w = pt + pb;                                        // h

        float conf = sqrtf(fast_sigmoid(cl_) * fast_sigmoid(bv));

        __builtin_nontemporal_store(r, reinterpret_cast<f4*>(out) + pix);
        __builtin_nontemporal_store((float)bi, out + (size_t)4 * NPIX + pix);
        __builtin_nontemporal_store(conf, out + (size_t)5 * NPIX + pix);
    }
}

extern "C" void kernel_launch(void* const* d_in, const int* in_sizes, int n_in,
                              void* d_out, int out_size, void* d_ws, size_t ws_size,
                              hipStream_t stream) {
    const float* t_ltrb        = (const float*)d_in[0];
    const float* center_logits = (const float*)d_in[1];
    const float* cls_logits    = (const float*)d_in[2];
    float* out = (float*)d_out;

    int threads = 256;
    long long total_threads = (long long)(NPIX / 2) * 4;   // 4 lanes per 2 pixels
    int blocks = (int)((total_threads + threads - 1) / threads);  // 4096
    fcos_decode_kernel<<<blocks, threads, 0, stream>>>(t_ltrb, center_logits, cls_logits, out);
}

// Round 2
// 236.403 us; speedup vs baseline: 1.0416x; 1.0416x over previous
//
#include <hip/hip_runtime.h>

// FCOS decode, level stride=8.
// Inputs:  t_ltrb [32,128,128,4] f32, center_logits [32,128,128,1] f32,
//          cls_logits [32,128,128,80] f32, img_h (unused), img_w (unused)
// Outputs (concat flat, all f32): xywh [nPix*4] | cls_idx [nPix] | conf [nPix]
//
// 4 lanes per *pair* of pixels: lane l issues 10 independent nontemporal
// float4 loads (5 per pixel); each 4-lane group covers full 64B segments ->
// fully coalesced wave loads, 10 loads in flight per lane.
//
// Round-2 state:
//  - NT loads RESTORED (round-1 post-mortem: the ~671 MB re-poison fill
//    evicts the entire LLC between iterations, so there is no input cache
//    residency; cached loads cost ~8 us vs NT streaming). All inputs and
//    outputs are single-use -> nt loads AND nt stores.
//  - Epilogue split across lanes 0 and 1 of each group (lane l owns pixel
//    p0+l; the XOR-reduce leaves both results in all 4 lanes) -> ltrb loads
//    and all output stores are 32-lane contiguous.
//  - ltrb/center loads hoisted above the shuffle reduce so their latency
//    hides under the cross-lane chain.

#define NB   32
#define NH   128
#define NW   128
#define NC   80
#define HWPX (NH * NW)          // 16384
#define NPIX (NB * HWPX)        // 524288

typedef float f4 __attribute__((ext_vector_type(4)));

__device__ __forceinline__ float fast_sigmoid(float x) {
    return 1.0f / (1.0f + __expf(-x));
}

__global__ __launch_bounds__(256) void fcos_decode_kernel(
    const float* __restrict__ t_ltrb,
    const float* __restrict__ center_logits,
    const float* __restrict__ cls_logits,
    float* __restrict__ out)
{
    int tid = blockIdx.x * blockDim.x + threadIdx.x;
    int grp = tid >> 2;          // each 4-lane group handles 2 pixels
    int l   = tid & 3;
    int p0  = grp * 2;
    if (p0 >= NPIX) return;

    const f4* cp0 = reinterpret_cast<const f4*>(cls_logits) + (size_t)p0 * (NC / 4);
    const f4* cp1 = cp0 + (NC / 4);

    // Issue all 10 independent loads up front (nontemporal: zero reuse).
    f4 va[5], vb[5];
    #pragma unroll
    for (int k = 0; k < 5; ++k) va[k] = __builtin_nontemporal_load(&cp0[k * 4 + l]);
    #pragma unroll
    for (int k = 0; k < 5; ++k) vb[k] = __builtin_nontemporal_load(&cp1[k * 4 + l]);

    // Epilogue operands: issue early so latency hides under the argmax+reduce.
    // Lane l<2 will own pixel p0+l.
    f4 t4 = {0.f, 0.f, 0.f, 0.f};
    float cl_ = 0.f;
    if (l < 2) {
        t4  = __builtin_nontemporal_load(reinterpret_cast<const f4*>(t_ltrb) + p0 + l);
        cl_ = __builtin_nontemporal_load(&center_logits[p0 + l]);
    }

    // Per-lane argmax (sigmoid monotonic -> argmax on raw logits; strict '>'
    // + ascending index = first occurrence, matching np.argmax).
    float b0 = -INFINITY, b1 = -INFINITY;
    int i0 = 0, i1 = 0;
    #pragma unroll
    for (int k = 0; k < 5; ++k) {
        int c = k * 16 + l * 4;
        f4 v = va[k];
        if (v.x > b0) { b0 = v.x; i0 = c + 0; }
        if (v.y > b0) { b0 = v.y; i0 = c + 1; }
        if (v.z > b0) { b0 = v.z; i0 = c + 2; }
        if (v.w > b0) { b0 = v.w; i0 = c + 3; }
        f4 w = vb[k];
        if (w.x > b1) { b1 = w.x; i1 = c + 0; }
        if (w.y > b1) { b1 = w.y; i1 = c + 1; }
        if (w.z > b1) { b1 = w.z; i1 = c + 2; }
        if (w.w > b1) { b1 = w.w; i1 = c + 3; }
    }
    // Cross-lane reduce over the 4-lane group; smaller index wins ties.
    // After both steps every lane in the group holds (b0,i0) and (b1,i1).
    #pragma unroll
    for (int m = 2; m >= 1; m >>= 1) {
        float ov0 = __shfl_xor(b0, m, 4);
        int   oi0 = __shfl_xor(i0, m, 4);
        if (ov0 > b0 || (ov0 == b0 && oi0 < i0)) { b0 = ov0; i0 = oi0; }
        float ov1 = __shfl_xor(b1, m, 4);
        int   oi1 = __shfl_xor(i1, m, 4);
        if (ov1 > b1 || (ov1 == b1 && oi1 < i1)) { b1 = ov1; i1 = oi1; }
    }

    if (l < 2) {
        int pix = p0 + l;                 // lane 0 -> p0, lane 1 -> p0+1
        float bv = l ? b1 : b0;
        int   bi = l ? i1 : i0;

        int pimg = pix & (HWPX - 1);
        int gy = pimg >> 7;
        int gx = pimg & (NW - 1);

        float pl = __expf(t4.x) * 8.0f;
        float pt = __expf(t4.y) * 8.0f;
        float pr = __expf(t4.z) * 8.0f;
        float pb = __expf(t4.w) * 8.0f;

        f4 r;
        r.x = ((float)gx * 8.0f + 4.0f) + (pr - pl) * 0.5f;  // cx
        r.y = ((float)gy * 8.0f + 4.0f) + (pb - pt) * 0.5f;  // cy
        r.z = pl + pr;                                        // w
        r.w = pt + pb;                                        // h

        float conf = sqrtf(fast_sigmoid(cl_) * fast_sigmoid(bv));

        __builtin_nontemporal_store(r, reinterpret_cast<f4*>(out) + pix);
        __builtin_nontemporal_store((float)bi, out + (size_t)4 * NPIX + pix);
        __builtin_nontemporal_store(conf, out + (size_t)5 * NPIX + pix);
    }
}

extern "C" void kernel_launch(void* const* d_in, const int* in_sizes, int n_in,
                              void* d_out, int out_size, void* d_ws, size_t ws_size,
                              hipStream_t stream) {
    const float* t_ltrb        = (const float*)d_in[0];
    const float* center_logits = (const float*)d_in[1];
    const float* cls_logits    = (const float*)d_in[2];
    float* out = (float*)d_out;

    int threads = 256;
    long long total_threads = (long long)(NPIX / 2) * 4;   // 4 lanes per 2 pixels
    int blocks = (int)((total_threads + threads - 1) / threads);  // 4096
    fcos_decode_kernel<<<blocks, threads, 0, stream>>>(t_ltrb, center_logits, cls_logits, out);
}

// Round 4
// 232.128 us; speedup vs baseline: 1.0608x; 1.0184x over previous
//
#include <hip/hip_runtime.h>

// FCOS decode, level stride=8.
// Inputs:  t_ltrb [32,128,128,4] f32, center_logits [32,128,128,1] f32,
//          cls_logits [32,128,128,80] f32, img_h (unused), img_w (unused)
// Outputs (concat flat, all f32): xywh [nPix*4] | cls_idx [nPix] | conf [nPix]
//
// Round-4 = round-3 kernel resubmitted (round-3 bench died on container
// acquisition, kernel never ran).
//
// Structure: 8 lanes per *pair* of pixels.
//  - lane l in [0,8) loads f4 index k*8+l (k=0..4) of the pair's contiguous
//    40-f4 (640B) cls block -> each load instruction covers full 128B cache
//    lines (8 groups x 128B segments per wave), and live cls data is only
//    20 VGPRs/lane (was 40) -> VGPR total ~50 -> 8 waves/SIMD occupancy.
//  - per-lane argmax is dual-track (a lane's 5 f4s split across the two
//    pixels; f4 20 is the pixel boundary so no f4 straddles). Only k=2 is
//    truly divergent; k={0,1} / {3,4} fold to px0 / px1 at compile time.
//  - cross-lane reduce: 3 shfl_xor rounds at width 8, both tracks;
//    tie -> smaller class index (np.argmax first-occurrence).
//  - NT loads + NT stores (round-1 A/B: the ~671 MB re-poison fill evicts
//    the whole LLC between iterations; cached loads cost ~11 us).
//  - epilogue on lanes 0,1 of each group (results present in all lanes
//    after the reduce); ltrb/center loads hoisted above the argmax.

#define NB   32
#define NH   128
#define NW   128
#define NC   80
#define HWPX (NH * NW)          // 16384
#define NPIX (NB * HWPX)        // 524288

typedef float f4 __attribute__((ext_vector_type(4)));

__device__ __forceinline__ float fast_sigmoid(float x) {
    return 1.0f / (1.0f + __expf(-x));
}

__global__ __launch_bounds__(256) void fcos_decode_kernel(
    const float* __restrict__ t_ltrb,
    const float* __restrict__ center_logits,
    const float* __restrict__ cls_logits,
    float* __restrict__ out)
{
    int tid = blockIdx.x * blockDim.x + threadIdx.x;
    int grp = tid >> 3;          // each 8-lane group handles 2 pixels
    int l   = tid & 7;
    int p0  = grp * 2;
    if (p0 >= NPIX) return;

    // 40 contiguous f4s cover both pixels' cls logits (pixel boundary = f4 20).
    const f4* cp = reinterpret_cast<const f4*>(cls_logits) + (size_t)p0 * (NC / 4);

    // 5 independent NT loads; instruction k covers bytes [k*128, k*128+128)
    // of each group's 640B block -> full-line segments, fully coalesced.
    f4 v[5];
    #pragma unroll
    for (int k = 0; k < 5; ++k) v[k] = __builtin_nontemporal_load(&cp[k * 8 + l]);

    // Epilogue operands: issue early so latency hides under the argmax.
    // Lane l<2 will own pixel p0+l.
    f4 t4 = {0.f, 0.f, 0.f, 0.f};
    float cl_ = 0.f;
    if (l < 2) {
        t4  = __builtin_nontemporal_load(reinterpret_cast<const f4*>(t_ltrb) + p0 + l);
        cl_ = __builtin_nontemporal_load(&center_logits[p0 + l]);
    }

    // Dual-track per-lane argmax (sigmoid monotonic -> argmax on raw logits;
    // strict '>' + ascending index = first occurrence, matching np.argmax).
    float b0 = -INFINITY, b1 = -INFINITY;
    int i0 = 0, i1 = 0;
    #pragma unroll
    for (int k = 0; k < 5; ++k) {
        int j = k * 8 + l;           // f4 index within the 40-f4 pair block
        f4 w = v[k];
        if (j < 20) {                // pixel p0, classes j*4 .. j*4+3
            int c = j * 4;
            if (w.x > b0) { b0 = w.x; i0 = c + 0; }
            if (w.y > b0) { b0 = w.y; i0 = c + 1; }
            if (w.z > b0) { b0 = w.z; i0 = c + 2; }
            if (w.w > b0) { b0 = w.w; i0 = c + 3; }
        } else {                     // pixel p0+1, classes (j-20)*4 ..
            int c = (j - 20) * 4;
            if (w.x > b1) { b1 = w.x; i1 = c + 0; }
            if (w.y > b1) { b1 = w.y; i1 = c + 1; }
            if (w.z > b1) { b1 = w.z; i1 = c + 2; }
            if (w.w > b1) { b1 = w.w; i1 = c + 3; }
        }
    }
    // Cross-lane reduce over the 8-lane group; smaller index wins ties.
    // After all rounds every lane holds the final (b0,i0) and (b1,i1).
    #pragma unroll
    for (int m = 4; m >= 1; m >>= 1) {
        float ov0 = __shfl_xor(b0, m, 8);
        int   oi0 = __shfl_xor(i0, m, 8);
        if (ov0 > b0 || (ov0 == b0 && oi0 < i0)) { b0 = ov0; i0 = oi0; }
        float ov1 = __shfl_xor(b1, m, 8);
        int   oi1 = __shfl_xor(i1, m, 8);
        if (ov1 > b1 || (ov1 == b1 && oi1 < i1)) { b1 = ov1; i1 = oi1; }
    }

    if (l < 2) {
        int pix = p0 + l;                 // lane 0 -> p0, lane 1 -> p0+1
        float bv = l ? b1 : b0;
        int   bi = l ? i1 : i0;

        int pimg = pix & (HWPX - 1);
        int gy = pimg >> 7;
        int gx = pimg & (NW - 1);

        float pl = __expf(t4.x) * 8.0f;
        float pt = __expf(t4.y) * 8.0f;
        float pr = __expf(t4.z) * 8.0f;
        float pb = __expf(t4.w) * 8.0f;

        f4 r;
        r.x = ((float)gx * 8.0f + 4.0f) + (pr - pl) * 0.5f;  // cx
        r.y = ((float)gy * 8.0f + 4.0f) + (pb - pt) * 0.5f;  // cy
        r.z = pl + pr;                                        // w
        r.w = pt + pb;                                        // h

        float conf = sqrtf(fast_sigmoid(cl_) * fast_sigmoid(bv));

        __builtin_nontemporal_store(r, reinterpret_cast<f4*>(out) + pix);
        __builtin_nontemporal_store((float)bi, out + (size_t)4 * NPIX + pix);
        __builtin_nontemporal_store(conf, out + (size_t)5 * NPIX + pix);
    }
}

extern "C" void kernel_launch(void* const* d_in, const int* in_sizes, int n_in,
                              void* d_out, int out_size, void* d_ws, size_t ws_size,
                              hipStream_t stream) {
    const float* t_ltrb        = (const float*)d_in[0];
    const float* center_logits = (const float*)d_in[1];
    const float* cls_logits    = (const float*)d_in[2];
    float* out = (float*)d_out;

    int threads = 256;
    long long total_threads = (long long)(NPIX / 2) * 8;   // 8 lanes per 2 pixels
    int blocks = (int)((total_threads + threads - 1) / threads);  // 8192
    fcos_decode_kernel<<<blocks, threads, 0, stream>>>(t_ltrb, center_logits, cls_logits, out);
}